// Round 2
// baseline (44355.423 us; speedup 1.0000x reference)
//
#include <hip/hip_runtime.h>
#include <hip/hip_bf16.h>
#include <hip/hip_fp16.h>

// ---------------------------------------------------------------------------
// LuxrNet: conv->conv->FFN (parallel branch) + 2-layer GRU over a 32768-step
// flattened scan (serial branch) + joiner + output head.
// ---------------------------------------------------------------------------

typedef _Float16 h2_t __attribute__((ext_vector_type(2)));

#if defined(__has_builtin)
#if __has_builtin(__builtin_amdgcn_fdot2)
#define HAVE_FDOT2 1
#endif
#endif

__device__ __forceinline__ h2_t f2h2bits(float x) {
  union { float f; h2_t h; } u; u.f = x; return u.h;
}

__device__ __forceinline__ float fdot2(h2_t a, h2_t b, float c) {
#ifdef HAVE_FDOT2
  return __builtin_amdgcn_fdot2(a, b, c, false);
#else
  return c + (float)a.x * (float)b.x + (float)a.y * (float)b.y;
#endif
}

__device__ __forceinline__ float sigmoidf_(float x) {
  return 1.f / (1.f + __expf(-x));
}
__device__ __forceinline__ float tanhf_(float x) {
  return 2.f / (1.f + __expf(-2.f * x)) - 1.f;
}

// ---------------------------------------------------------------------------
// conv1: in (512,10,30,30), w (64,10,8,8), stride 2 -> out (512,64,12,12), relu
// thread per output element.
// ---------------------------------------------------------------------------
__global__ __launch_bounds__(256) void conv1_k(
    const float* __restrict__ in, const float* __restrict__ w,
    const float* __restrict__ bias, float* __restrict__ out) {
  int idx = blockIdx.x * 256 + threadIdx.x;     // 512*64*144 total, exact
  int pos = idx % 144;
  int co  = (idx / 144) & 63;
  int b   = idx / (144 * 64);
  int oh = pos / 12, ow = pos % 12;
  const float* ip = in + (size_t)b * 9000 + (oh * 2) * 30 + ow * 2;
  const float* wp = w + co * 640;
  float acc = bias[co];
  for (int ci = 0; ci < 10; ci++) {
#pragma unroll
    for (int kh = 0; kh < 8; kh++) {
      const float* r  = ip + ci * 900 + kh * 30;
      const float* wr = wp + ci * 64 + kh * 8;
#pragma unroll
      for (int kw = 0; kw < 8; kw++) acc += r[kw] * wr[kw];
    }
  }
  out[idx] = fmaxf(acc, 0.f);
}

// ---------------------------------------------------------------------------
// conv2: in (512,64,12,12), w (128,64,4,4), stride 2 -> out (512,128,5,5), relu
// ---------------------------------------------------------------------------
__global__ __launch_bounds__(256) void conv2_k(
    const float* __restrict__ in, const float* __restrict__ w,
    const float* __restrict__ bias, float* __restrict__ out) {
  int idx = blockIdx.x * 256 + threadIdx.x;     // 512*128*25 total, exact
  int pos = idx % 25;
  int co  = (idx / 25) & 127;
  int b   = idx / 3200;
  int oh = pos / 5, ow = pos % 5;
  const float* ip = in + (size_t)b * 9216 + (oh * 2) * 12 + ow * 2;
  const float* wp = w + co * 1024;
  float acc = bias[co];
  for (int ci = 0; ci < 64; ci++) {
#pragma unroll
    for (int kh = 0; kh < 4; kh++) {
      const float* r  = ip + ci * 144 + kh * 12;
      const float* wr = wp + ci * 16 + kh * 4;
#pragma unroll
      for (int kw = 0; kw < 4; kw++) acc += r[kw] * wr[kw];
    }
  }
  out[idx] = fmaxf(acc, 0.f);
}

// ---------------------------------------------------------------------------
// Generic fp32 GEMM: C[m*ldc+n] = bias[n] + sum_k X[m*K+k] * W[n*K+k]
// Requires M%64==0, N%64==0, K%16==0. 64x64 tile, 256 threads, 4x4 micro.
// ---------------------------------------------------------------------------
__global__ __launch_bounds__(256) void gemm_xwt(
    const float* __restrict__ X, const float* __restrict__ W,
    const float* __restrict__ bias, float* __restrict__ C,
    int M, int N, int K, int ldc, int relu) {
  __shared__ float Xs[16][68];
  __shared__ float Ws[16][68];
  int tid = threadIdx.x;
  int m0 = blockIdx.y * 64, n0 = blockIdx.x * 64;
  int lr = tid >> 2;            // 0..63
  int lc = (tid & 3) << 2;      // 0,4,8,12
  int tm = tid >> 4, tn = tid & 15;
  float acc[4][4] = {};
  for (int k0 = 0; k0 < K; k0 += 16) {
    const float4 xv = *(const float4*)(X + (size_t)(m0 + lr) * K + k0 + lc);
    const float4 wv = *(const float4*)(W + (size_t)(n0 + lr) * K + k0 + lc);
    Xs[lc + 0][lr] = xv.x; Xs[lc + 1][lr] = xv.y;
    Xs[lc + 2][lr] = xv.z; Xs[lc + 3][lr] = xv.w;
    Ws[lc + 0][lr] = wv.x; Ws[lc + 1][lr] = wv.y;
    Ws[lc + 2][lr] = wv.z; Ws[lc + 3][lr] = wv.w;
    __syncthreads();
#pragma unroll
    for (int kk = 0; kk < 16; kk++) {
      float a[4], bb[4];
#pragma unroll
      for (int i = 0; i < 4; i++) a[i] = Xs[kk][tm * 4 + i];
#pragma unroll
      for (int j = 0; j < 4; j++) bb[j] = Ws[kk][tn * 4 + j];
#pragma unroll
      for (int i = 0; i < 4; i++)
#pragma unroll
        for (int j = 0; j < 4; j++) acc[i][j] += a[i] * bb[j];
    }
    __syncthreads();
  }
#pragma unroll
  for (int i = 0; i < 4; i++) {
    int m = m0 + tm * 4 + i;
#pragma unroll
    for (int j = 0; j < 4; j++) {
      int n = n0 + tn * 4 + j;
      float v = acc[i][j] + bias[n];
      if (relu) v = fmaxf(v, 0.f);
      C[(size_t)m * ldc + n] = v;
    }
  }
}

// ---------------------------------------------------------------------------
// GRU scan. One workgroup of 512 threads, S=32768 sequential steps.
// Threads 0..383: own one gh row, whh row pre-packed to 64 half2 regs,
//   matvec = 16 ds_read_b128 (uniform addr -> broadcast, conflict-free)
//   + 64 v_dot2_f32_f16 (f32 accumulate).
// Threads 0..127 additionally run the gates; h kept fp32 in a register,
//   f16 copy in LDS for the matvec.
// Threads 384..511: distance-2 prefetch of the per-step input (x or gi row).
// LAYER==0: gi computed on the fly from units_features (K=8), writes h1.
// LAYER==1: gi precomputed (GEMM); writes last 512 h's into jx cols 512..639.
// ---------------------------------------------------------------------------
template <int LAYER>
__global__ __launch_bounds__(512, 1) void gru_scan(
    const float* __restrict__ gi,    // LAYER1: (S,384) incl. bih
    const float* __restrict__ xin,   // LAYER0: units_features (512,64,8)
    const float* __restrict__ wih,   // LAYER0: (384,8)
    const float* __restrict__ bih,   // LAYER0: (384)
    const float* __restrict__ whh,   // (384,128)
    const float* __restrict__ bhh,   // (384)
    float* __restrict__ h_out,       // LAYER0: h1 (S,128)
    float* __restrict__ jx) {        // LAYER1: (512,640) concat buffer
  const int S = 32768;
  const int t = threadIdx.x;

  alignas(16) __shared__ _Float16 hH[128];  // f16 h for matvec
  __shared__ float gh[384];
  __shared__ float xb[3][8];                // LAYER0 input ring
  __shared__ float gib[3][384];             // LAYER1 input ring

  // preload recurrent weights (64 half2 regs) + bias
  h2_t w2[64];
  float bh = 0.f;
  if (t < 384) {
    bh = bhh[t];
    const float* wr = whh + t * 128;
#pragma unroll
    for (int k = 0; k < 64; k++) {
      h2_t v; v.x = (_Float16)wr[2 * k]; v.y = (_Float16)wr[2 * k + 1];
      w2[k] = v;
    }
  }
  // gate-thread extras
  float wi[3][8];
  float bi[3];
  float hreg = 0.f;
  if (LAYER == 0 && t < 128) {
#pragma unroll
    for (int g = 0; g < 3; g++) {
      bi[g] = bih[t + 128 * g];
#pragma unroll
      for (int k = 0; k < 8; k++) wi[g][k] = wih[(t + 128 * g) * 8 + k];
    }
  }
  if (t < 128) hH[t] = (_Float16)0.f;
  // prologue: prefetch step 0 and 1 inputs
  if (LAYER == 0) {
    if (t >= 384 && t < 392) {
      int f = t - 384;
      for (int p = 0; p < 2; p++)
        xb[p][f] = xin[(size_t)p * 512 + f];   // b=p, t=0
    }
  } else {
    if (t >= 384) {
      int j = t - 384;
      for (int p = 0; p < 2; p++) {
        size_t base = (size_t)p * 384;
        gib[p][j] = gi[base + j];
        gib[p][j + 128] = gi[base + j + 128];
        gib[p][j + 256] = gi[base + j + 256];
      }
    }
  }
  __syncthreads();

  for (int s = 0; s < S; s++) {
    const int cur = s % 3;
    const int nxt = (s + 2) % 3;
    float gsum0 = 0.f, gsum1 = 0.f, gsum2 = 0.f;

    if (t < 384) {
      // --- matvec gh[t] = bhh[t] + whh[t,:] . h  (f16 dot2, f32 acc) ---
      const float4* h4 = (const float4*)hH;
      float a0 = bh, a1 = 0.f, a2 = 0.f, a3 = 0.f;
#pragma unroll
      for (int q = 0; q < 16; q++) {
        float4 blk = h4[q];
        a0 = fdot2(w2[4 * q + 0], f2h2bits(blk.x), a0);
        a1 = fdot2(w2[4 * q + 1], f2h2bits(blk.y), a1);
        a2 = fdot2(w2[4 * q + 2], f2h2bits(blk.z), a2);
        a3 = fdot2(w2[4 * q + 3], f2h2bits(blk.w), a3);
      }
      gh[t] = (a0 + a1) + (a2 + a3);
      if (t < 128) {
        // gate threads gather this step's gi
        if (LAYER == 0) {
#pragma unroll
          for (int g = 0; g < 3; g++) {
            float a = bi[g];
#pragma unroll
            for (int k = 0; k < 8; k++) a += wi[g][k] * xb[cur][k];
            if (g == 0) gsum0 = a; else if (g == 1) gsum1 = a; else gsum2 = a;
          }
        } else {
          gsum0 = gib[cur][t];
          gsum1 = gib[cur][t + 128];
          gsum2 = gib[cur][t + 256];
        }
      }
    } else if (s + 2 < S) {
      // --- distance-2 input prefetch ---
      if (LAYER == 0) {
        if (t < 392) {
          int f = t - 384;
          int sp = s + 2;
          xb[nxt][f] = xin[(size_t)(sp & 511) * 512 + (sp >> 9) * 8 + f];
        }
      } else {
        int j = t - 384;
        size_t base = (size_t)(s + 2) * 384;
        gib[nxt][j] = gi[base + j];
        gib[nxt][j + 128] = gi[base + j + 128];
        gib[nxt][j + 256] = gi[base + j + 256];
      }
    }
    __syncthreads();  // B1: gh visible

    if (t < 128) {
      float r = sigmoidf_(gsum0 + gh[t]);
      float z = sigmoidf_(gsum1 + gh[t + 128]);
      float n = tanhf_(gsum2 + r * gh[t + 256]);
      float hn = (1.f - z) * n + z * hreg;
      hreg = hn;
      hH[t] = (_Float16)hn;
      if (LAYER == 0) {
        h_out[(size_t)s * 128 + t] = hn;
      } else if (s >= S - 512) {
        jx[(size_t)(s - (S - 512)) * 640 + 512 + t] = hn;
      }
    }
    __syncthreads();  // B2: new hH visible for next step
  }
}

// ---------------------------------------------------------------------------
// out head: out[b,:] = relu(hidden[b,:]) @ out_w.T + out_b (relu pre-applied)
// ---------------------------------------------------------------------------
__global__ __launch_bounds__(64) void out_k(
    const float* __restrict__ hidden, const float* __restrict__ ow,
    const float* __restrict__ ob, float* __restrict__ out) {
  __shared__ float hrow[512];
  int b = blockIdx.x, t = threadIdx.x;
  float4* h4 = (float4*)hrow;
  const float4* src = (const float4*)(hidden + (size_t)b * 512);
  h4[t] = src[t];
  h4[t + 64] = src[t + 64];
  __syncthreads();
  if (t < 12) {
    float acc = ob[t];
    const float* wr = ow + t * 512;
    for (int k = 0; k < 512; k++) acc += hrow[k] * wr[k];
    out[(size_t)b * 12 + t] = acc;
  }
}

// ---------------------------------------------------------------------------
extern "C" void kernel_launch(void* const* d_in, const int* in_sizes, int n_in,
                              void* d_out, int out_size, void* d_ws,
                              size_t ws_size, hipStream_t stream) {
  const float* gf    = (const float*)d_in[0];   // (512,10,30,30)
  const float* uf    = (const float*)d_in[1];   // (512,64,8)
  const float* c1w   = (const float*)d_in[2];
  const float* c1b   = (const float*)d_in[3];
  const float* c2w   = (const float*)d_in[4];
  const float* c2b   = (const float*)d_in[5];
  const float* ffw   = (const float*)d_in[6];
  const float* ffb   = (const float*)d_in[7];
  const float* wih0  = (const float*)d_in[8];
  const float* whh0  = (const float*)d_in[9];
  const float* bih0  = (const float*)d_in[10];
  const float* bhh0  = (const float*)d_in[11];
  const float* wih1  = (const float*)d_in[12];
  const float* whh1  = (const float*)d_in[13];
  const float* bih1  = (const float*)d_in[14];
  const float* bhh1  = (const float*)d_in[15];
  const float* jw    = (const float*)d_in[16];
  const float* jb    = (const float*)d_in[17];
  const float* ow    = (const float*)d_in[18];
  const float* ob    = (const float*)d_in[19];
  float* outp = (float*)d_out;                  // (512,12)

  // workspace layout (floats). conv buffers time-share the gi1 region:
  // conv1o/conv2o are dead before gi1 is first written (stream-ordered).
  float* ws     = (float*)d_ws;
  float* gi1    = ws;                 // 32768*384 = 12,582,912 f
  float* conv1o = ws;                 //  4,718,592 f (aliases gi1, earlier in time)
  float* conv2o = ws + 4718592;       //  1,638,400 f (aliases gi1, earlier in time)
  float* h1     = ws + 12582912;      //  4,194,304 f
  float* jx     = h1 + 4194304;       //  512*640 = 327,680 f
  float* hidden = jx + 327680;        //  512*512 = 262,144 f
  // total: 17,367,040 floats = ~66.3 MB

  conv1_k<<<18432, 256, 0, stream>>>(gf, c1w, c1b, conv1o);
  conv2_k<<<6400, 256, 0, stream>>>(conv1o, c2w, c2b, conv2o);
  // glob = conv2o(512,3200) @ ffw.T + ffb -> jx cols [0,512)
  gemm_xwt<<<dim3(8, 8), 256, 0, stream>>>(conv2o, ffw, ffb, jx,
                                           512, 512, 3200, 640, 0);
  // GRU layer 0 (gi computed on the fly from units_features)
  gru_scan<0><<<1, 512, 0, stream>>>(nullptr, uf, wih0, bih0, whh0, bhh0,
                                     h1, nullptr);
  // gi1 = h1(32768,128) @ wih1.T + bih1
  gemm_xwt<<<dim3(6, 512), 256, 0, stream>>>(h1, wih1, bih1, gi1,
                                             32768, 384, 128, 384, 0);
  // GRU layer 1, writes last 512 h's into jx cols [512,640)
  gru_scan<1><<<1, 512, 0, stream>>>(gi1, nullptr, nullptr, nullptr,
                                     whh1, bhh1, nullptr, jx);
  // hidden = relu(jx(512,640) @ jw.T + jb)
  gemm_xwt<<<dim3(8, 8), 256, 0, stream>>>(jx, jw, jb, hidden,
                                           512, 512, 640, 512, 1);
  out_k<<<512, 64, 0, stream>>>(hidden, ow, ob, outp);
}

// Round 3
// 35115.735 us; speedup vs baseline: 1.2631x; 1.2631x over previous
//
#include <hip/hip_runtime.h>
#include <hip/hip_bf16.h>
#include <hip/hip_fp16.h>

// ---------------------------------------------------------------------------
// LuxrNet: conv->conv->FFN (parallel branch) + 2-layer GRU over a 32768-step
// flattened scan (serial branch) + joiner + output head.
// Round 3: scan rewritten as 256-thread pair-split matvec, 1 barrier/step
// (lgkmcnt-only), register gi prefetch, gi0 precomputed by GEMM.
// ---------------------------------------------------------------------------

typedef _Float16 h2_t __attribute__((ext_vector_type(2)));

#if defined(__has_builtin)
#if __has_builtin(__builtin_amdgcn_fdot2)
#define HAVE_FDOT2 1
#endif
#endif

__device__ __forceinline__ h2_t f2h2bits(float x) {
  union { float f; h2_t h; } u; u.f = x; return u.h;
}

__device__ __forceinline__ float fdot2(h2_t a, h2_t b, float c) {
#ifdef HAVE_FDOT2
  return __builtin_amdgcn_fdot2(a, b, c, false);
#else
  return c + (float)a.x * (float)b.x + (float)a.y * (float)b.y;
#endif
}

__device__ __forceinline__ float sigmoidf_(float x) {
  return 1.f / (1.f + __expf(-x));
}
__device__ __forceinline__ float tanhf_(float x) {
  return 2.f / (1.f + __expf(-2.f * x)) - 1.f;
}

// ---------------------------------------------------------------------------
// conv1: in (512,10,30,30), w (64,10,8,8), stride 2 -> out (512,64,12,12), relu
// ---------------------------------------------------------------------------
__global__ __launch_bounds__(256) void conv1_k(
    const float* __restrict__ in, const float* __restrict__ w,
    const float* __restrict__ bias, float* __restrict__ out) {
  int idx = blockIdx.x * 256 + threadIdx.x;     // 512*64*144 total, exact
  int pos = idx % 144;
  int co  = (idx / 144) & 63;
  int b   = idx / (144 * 64);
  int oh = pos / 12, ow = pos % 12;
  const float* ip = in + (size_t)b * 9000 + (oh * 2) * 30 + ow * 2;
  const float* wp = w + co * 640;
  float acc = bias[co];
  for (int ci = 0; ci < 10; ci++) {
#pragma unroll
    for (int kh = 0; kh < 8; kh++) {
      const float* r  = ip + ci * 900 + kh * 30;
      const float* wr = wp + ci * 64 + kh * 8;
#pragma unroll
      for (int kw = 0; kw < 8; kw++) acc += r[kw] * wr[kw];
    }
  }
  out[idx] = fmaxf(acc, 0.f);
}

// ---------------------------------------------------------------------------
// conv2: in (512,64,12,12), w (128,64,4,4), stride 2 -> out (512,128,5,5), relu
// ---------------------------------------------------------------------------
__global__ __launch_bounds__(256) void conv2_k(
    const float* __restrict__ in, const float* __restrict__ w,
    const float* __restrict__ bias, float* __restrict__ out) {
  int idx = blockIdx.x * 256 + threadIdx.x;     // 512*128*25 total, exact
  int pos = idx % 25;
  int co  = (idx / 25) & 127;
  int b   = idx / 3200;
  int oh = pos / 5, ow = pos % 5;
  const float* ip = in + (size_t)b * 9216 + (oh * 2) * 12 + ow * 2;
  const float* wp = w + co * 1024;
  float acc = bias[co];
  for (int ci = 0; ci < 64; ci++) {
#pragma unroll
    for (int kh = 0; kh < 4; kh++) {
      const float* r  = ip + ci * 144 + kh * 12;
      const float* wr = wp + ci * 16 + kh * 4;
#pragma unroll
      for (int kw = 0; kw < 4; kw++) acc += r[kw] * wr[kw];
    }
  }
  out[idx] = fmaxf(acc, 0.f);
}

// ---------------------------------------------------------------------------
// Generic fp32 GEMM: C[m*ldc+n] = bias[n] + sum_k X[m*K+k] * W[n*K+k]
// Requires M%64==0, N%64==0, K%16==0. 64x64 tile, 256 threads, 4x4 micro.
// ---------------------------------------------------------------------------
__global__ __launch_bounds__(256) void gemm_xwt(
    const float* __restrict__ X, const float* __restrict__ W,
    const float* __restrict__ bias, float* __restrict__ C,
    int M, int N, int K, int ldc, int relu) {
  __shared__ float Xs[16][68];
  __shared__ float Ws[16][68];
  int tid = threadIdx.x;
  int m0 = blockIdx.y * 64, n0 = blockIdx.x * 64;
  int lr = tid >> 2;            // 0..63
  int lc = (tid & 3) << 2;      // 0,4,8,12
  int tm = tid >> 4, tn = tid & 15;
  float acc[4][4] = {};
  for (int k0 = 0; k0 < K; k0 += 16) {
    const float4 xv = *(const float4*)(X + (size_t)(m0 + lr) * K + k0 + lc);
    const float4 wv = *(const float4*)(W + (size_t)(n0 + lr) * K + k0 + lc);
    Xs[lc + 0][lr] = xv.x; Xs[lc + 1][lr] = xv.y;
    Xs[lc + 2][lr] = xv.z; Xs[lc + 3][lr] = xv.w;
    Ws[lc + 0][lr] = wv.x; Ws[lc + 1][lr] = wv.y;
    Ws[lc + 2][lr] = wv.z; Ws[lc + 3][lr] = wv.w;
    __syncthreads();
#pragma unroll
    for (int kk = 0; kk < 16; kk++) {
      float a[4], bb[4];
#pragma unroll
      for (int i = 0; i < 4; i++) a[i] = Xs[kk][tm * 4 + i];
#pragma unroll
      for (int j = 0; j < 4; j++) bb[j] = Ws[kk][tn * 4 + j];
#pragma unroll
      for (int i = 0; i < 4; i++)
#pragma unroll
        for (int j = 0; j < 4; j++) acc[i][j] += a[i] * bb[j];
    }
    __syncthreads();
  }
#pragma unroll
  for (int i = 0; i < 4; i++) {
    int m = m0 + tm * 4 + i;
#pragma unroll
    for (int j = 0; j < 4; j++) {
      int n = n0 + tn * 4 + j;
      float v = acc[i][j] + bias[n];
      if (relu) v = fmaxf(v, 0.f);
      C[(size_t)m * ldc + n] = v;
    }
  }
}

// ---------------------------------------------------------------------------
// gi0 = seq @ wih0^T + bih0 where seq[s] = uf[s&511, s>>9, :]  (K=8).
// Block: 384 threads (one per output col), 32 consecutive s per block.
// ---------------------------------------------------------------------------
__global__ __launch_bounds__(384) void gi0_k(
    const float* __restrict__ uf,   // (512,64,8)
    const float* __restrict__ wih,  // (384,8)
    const float* __restrict__ bih,  // (384)
    float* __restrict__ gi) {       // (32768,384)
  int n = threadIdx.x;
  int s0 = blockIdx.x * 32;
  __shared__ float xs[32][8];
  if (n < 256) {
    int ss = s0 + (n >> 3);
    int k = n & 7;
    xs[n >> 3][k] = uf[(size_t)(ss & 511) * 512 + (ss >> 9) * 8 + k];
  }
  float w[8];
#pragma unroll
  for (int k = 0; k < 8; k++) w[k] = wih[n * 8 + k];
  float b = bih[n];
  __syncthreads();
#pragma unroll 4
  for (int i = 0; i < 32; i++) {
    float a = b;
#pragma unroll
    for (int k = 0; k < 8; k++) a += w[k] * xs[i][k];
    gi[(size_t)(s0 + i) * 384 + n] = a;
  }
}

// ---------------------------------------------------------------------------
// GRU scan, round-3 structure. 256 threads = 128 output pairs.
// Lane pair (2o, 2o+1) splits K=128: each thread holds half-rows of whh for
// all 3 gates as 96 packed-f16 regs -> 96 v_dot2_f32_f16, combined with one
// __shfl_xor per gate. h ping-pongs between hbuf[0]/hbuf[1] (one barrier per
// step, lgkmcnt-only so global gi prefetch stays in flight). gi[s] rows are
// prefetched into registers ~2 steps ahead (reload issued after consumption).
// ---------------------------------------------------------------------------
#define GRU_STEP(HIN, HOUT, G0, G1, G2, SIDX)                                 \
  {                                                                           \
    const float4* hp4 = (const float4*)(&HIN[half * 64]);                     \
    float ar = br, az = bz, an = bn;                                          \
    _Pragma("unroll")                                                         \
    for (int q = 0; q < 8; q++) {                                             \
      float4 blk = hp4[q];                                                    \
      h2_t x0 = f2h2bits(blk.x), x1 = f2h2bits(blk.y);                        \
      h2_t x2 = f2h2bits(blk.z), x3 = f2h2bits(blk.w);                        \
      ar = fdot2(wr[4*q+0], x0, ar); az = fdot2(wz[4*q+0], x0, az);           \
      an = fdot2(wn[4*q+0], x0, an);                                          \
      ar = fdot2(wr[4*q+1], x1, ar); az = fdot2(wz[4*q+1], x1, az);           \
      an = fdot2(wn[4*q+1], x1, an);                                          \
      ar = fdot2(wr[4*q+2], x2, ar); az = fdot2(wz[4*q+2], x2, az);           \
      an = fdot2(wn[4*q+2], x2, an);                                          \
      ar = fdot2(wr[4*q+3], x3, ar); az = fdot2(wz[4*q+3], x3, az);           \
      an = fdot2(wn[4*q+3], x3, an);                                          \
    }                                                                         \
    ar += __shfl_xor(ar, 1); az += __shfl_xor(az, 1); an += __shfl_xor(an, 1);\
    float r = sigmoidf_((G0) + ar);                                           \
    float z = sigmoidf_((G1) + az);                                           \
    float n = tanhf_((G2) + r * an);                                          \
    float hn = (1.f - z) * n + z * hreg;                                      \
    hreg = hn;                                                                \
    HOUT[o] = (_Float16)hn;                                                   \
    if (LAYER == 0) {                                                         \
      if (half == 0) h_out[(size_t)(SIDX) * 128 + o] = hn;                    \
    } else if ((SIDX) >= S - 512) {                                           \
      if (half == 0) jx[(size_t)((SIDX) - (S - 512)) * 640 + 512 + o] = hn;   \
    }                                                                         \
  }

#define GRU_BARRIER()                                                         \
  __builtin_amdgcn_sched_barrier(0);                                          \
  asm volatile("s_waitcnt lgkmcnt(0)" ::: "memory");                          \
  __builtin_amdgcn_s_barrier();                                               \
  __builtin_amdgcn_sched_barrier(0);

template <int LAYER>
__global__ __launch_bounds__(256, 1) void gru_scan2(
    const float* __restrict__ gi,    // (S,384), includes bih
    const float* __restrict__ whh,   // (384,128)
    const float* __restrict__ bhh,   // (384)
    float* __restrict__ h_out,       // LAYER0: h1 (S,128)
    float* __restrict__ jx) {        // LAYER1: (512,640), cols 512..639
  const int S = 32768;
  const int t = threadIdx.x;
  const int o = t >> 1;      // output index 0..127
  const int half = t & 1;    // K-half 0/1

  __shared__ _Float16 hbuf0[128];
  __shared__ _Float16 hbuf1[128];

  // preload f16-packed recurrent weights: 32 h2 per gate (this thread's half)
  h2_t wr[32], wz[32], wn[32];
  {
    const float2* pr = (const float2*)(whh + (size_t)(o)       * 128 + half * 64);
    const float2* pz = (const float2*)(whh + (size_t)(128 + o) * 128 + half * 64);
    const float2* pn = (const float2*)(whh + (size_t)(256 + o) * 128 + half * 64);
#pragma unroll
    for (int k = 0; k < 32; k++) {
      float2 a = pr[k], b = pz[k], c = pn[k];
      h2_t va; va.x = (_Float16)a.x; va.y = (_Float16)a.y; wr[k] = va;
      h2_t vb; vb.x = (_Float16)b.x; vb.y = (_Float16)b.y; wz[k] = vb;
      h2_t vc; vc.x = (_Float16)c.x; vc.y = (_Float16)c.y; wn[k] = vc;
    }
  }
  // bhh folded into the matvec accumulator init (half 0 only, to count once)
  float br = half ? 0.f : bhh[o];
  float bz = half ? 0.f : bhh[128 + o];
  float bn = half ? 0.f : bhh[256 + o];

  float hreg = 0.f;
  if (t < 128) { hbuf0[t] = (_Float16)0.f; }

  // register prefetch of gi rows for steps 0 and 1
  float gA0 = gi[o],       gA1 = gi[128 + o],       gA2 = gi[256 + o];
  float gB0 = gi[384 + o], gB1 = gi[384 + 128 + o], gB2 = gi[384 + 256 + o];
  __syncthreads();

  for (int s = 0; s < S; s += 2) {
    GRU_STEP(hbuf0, hbuf1, gA0, gA1, gA2, s);
    { // reload gA for step s+2 (issued after consumption -> depth-2 prefetch)
      int sp = (s + 2 < S) ? s + 2 : S - 1;
      const float* gp = gi + (size_t)sp * 384 + o;
      gA0 = gp[0]; gA1 = gp[128]; gA2 = gp[256];
    }
    GRU_BARRIER();
    GRU_STEP(hbuf1, hbuf0, gB0, gB1, gB2, s + 1);
    {
      int sp = (s + 3 < S) ? s + 3 : S - 1;
      const float* gp = gi + (size_t)sp * 384 + o;
      gB0 = gp[0]; gB1 = gp[128]; gB2 = gp[256];
    }
    GRU_BARRIER();
  }
}

// ---------------------------------------------------------------------------
// out head: out[b,:] = hidden[b,:] @ out_w.T + out_b (relu pre-applied)
// ---------------------------------------------------------------------------
__global__ __launch_bounds__(64) void out_k(
    const float* __restrict__ hidden, const float* __restrict__ ow,
    const float* __restrict__ ob, float* __restrict__ out) {
  __shared__ float hrow[512];
  int b = blockIdx.x, t = threadIdx.x;
  float4* h4 = (float4*)hrow;
  const float4* src = (const float4*)(hidden + (size_t)b * 512);
  h4[t] = src[t];
  h4[t + 64] = src[t + 64];
  __syncthreads();
  if (t < 12) {
    float acc = ob[t];
    const float* wr = ow + t * 512;
    for (int k = 0; k < 512; k++) acc += hrow[k] * wr[k];
    out[(size_t)b * 12 + t] = acc;
  }
}

// ---------------------------------------------------------------------------
extern "C" void kernel_launch(void* const* d_in, const int* in_sizes, int n_in,
                              void* d_out, int out_size, void* d_ws,
                              size_t ws_size, hipStream_t stream) {
  const float* gf    = (const float*)d_in[0];   // (512,10,30,30)
  const float* uf    = (const float*)d_in[1];   // (512,64,8)
  const float* c1w   = (const float*)d_in[2];
  const float* c1b   = (const float*)d_in[3];
  const float* c2w   = (const float*)d_in[4];
  const float* c2b   = (const float*)d_in[5];
  const float* ffw   = (const float*)d_in[6];
  const float* ffb   = (const float*)d_in[7];
  const float* wih0  = (const float*)d_in[8];
  const float* whh0  = (const float*)d_in[9];
  const float* bih0  = (const float*)d_in[10];
  const float* bhh0  = (const float*)d_in[11];
  const float* wih1  = (const float*)d_in[12];
  const float* whh1  = (const float*)d_in[13];
  const float* bih1  = (const float*)d_in[14];
  const float* bhh1  = (const float*)d_in[15];
  const float* jw    = (const float*)d_in[16];
  const float* jb    = (const float*)d_in[17];
  const float* ow    = (const float*)d_in[18];
  const float* ob    = (const float*)d_in[19];
  float* outp = (float*)d_out;                  // (512,12)

  // workspace layout (floats). gi buffer time-shares with conv scratch
  // (conv1o/conv2o dead before gi0 is written) and is reused for gi1.
  float* ws     = (float*)d_ws;
  float* gi     = ws;                 // 32768*384 = 12,582,912 f
  float* conv1o = ws;                 //  4,718,592 f (aliases gi, earlier)
  float* conv2o = ws + 4718592;       //  1,638,400 f (aliases gi, earlier)
  float* h1     = ws + 12582912;      //  4,194,304 f
  float* jx     = h1 + 4194304;       //  512*640 = 327,680 f
  float* hidden = jx + 327680;        //  512*512 = 262,144 f
  // total: 17,367,040 floats = ~66.3 MB

  conv1_k<<<18432, 256, 0, stream>>>(gf, c1w, c1b, conv1o);
  conv2_k<<<6400, 256, 0, stream>>>(conv1o, c2w, c2b, conv2o);
  // glob = conv2o(512,3200) @ ffw.T + ffb -> jx cols [0,512)
  gemm_xwt<<<dim3(8, 8), 256, 0, stream>>>(conv2o, ffw, ffb, jx,
                                           512, 512, 3200, 640, 0);
  // gi0 = seq @ wih0^T + bih0  (overwrites conv scratch, now dead)
  gi0_k<<<1024, 384, 0, stream>>>(uf, wih0, bih0, gi);
  // GRU layer 0
  gru_scan2<0><<<1, 256, 0, stream>>>(gi, whh0, bhh0, h1, nullptr);
  // gi1 = h1(32768,128) @ wih1.T + bih1  (overwrites gi0, now dead)
  gemm_xwt<<<dim3(6, 512), 256, 0, stream>>>(h1, wih1, bih1, gi,
                                             32768, 384, 128, 384, 0);
  // GRU layer 1, writes last 512 h's into jx cols [512,640)
  gru_scan2<1><<<1, 256, 0, stream>>>(gi, whh1, bhh1, nullptr, jx);
  // hidden = relu(jx(512,640) @ jw.T + jb)
  gemm_xwt<<<dim3(8, 8), 256, 0, stream>>>(jx, jw, jb, hidden,
                                           512, 512, 640, 512, 1);
  out_k<<<512, 64, 0, stream>>>(hidden, ow, ob, outp);
}

// Round 4
// 34040.140 us; speedup vs baseline: 1.3030x; 1.0316x over previous
//
#include <hip/hip_runtime.h>
#include <hip/hip_bf16.h>
#include <hip/hip_fp16.h>

// ---------------------------------------------------------------------------
// LuxrNet: conv->conv->FFN (parallel branch) + 2-layer GRU over a 32768-step
// flattened scan (serial branch) + joiner + output head.
// Round 4: scan = 256-thread pair-split matvec, 1 barrier/step (lgkmcnt-only),
// DEPTH-4 register prefetch of gi rows (covers ~900-cyc HBM miss latency),
// rolling-pointer addressing. gi0 precomputed by GEMM.
// ---------------------------------------------------------------------------

typedef _Float16 h2_t __attribute__((ext_vector_type(2)));

#if defined(__has_builtin)
#if __has_builtin(__builtin_amdgcn_fdot2)
#define HAVE_FDOT2 1
#endif
#endif

__device__ __forceinline__ h2_t f2h2bits(float x) {
  union { float f; h2_t h; } u; u.f = x; return u.h;
}

__device__ __forceinline__ float fdot2(h2_t a, h2_t b, float c) {
#ifdef HAVE_FDOT2
  return __builtin_amdgcn_fdot2(a, b, c, false);
#else
  return c + (float)a.x * (float)b.x + (float)a.y * (float)b.y;
#endif
}

__device__ __forceinline__ float sigmoidf_(float x) {
  return 1.f / (1.f + __expf(-x));
}
__device__ __forceinline__ float tanhf_(float x) {
  return 2.f / (1.f + __expf(-2.f * x)) - 1.f;
}

// ---------------------------------------------------------------------------
// conv1: in (512,10,30,30), w (64,10,8,8), stride 2 -> out (512,64,12,12), relu
// ---------------------------------------------------------------------------
__global__ __launch_bounds__(256) void conv1_k(
    const float* __restrict__ in, const float* __restrict__ w,
    const float* __restrict__ bias, float* __restrict__ out) {
  int idx = blockIdx.x * 256 + threadIdx.x;     // 512*64*144 total, exact
  int pos = idx % 144;
  int co  = (idx / 144) & 63;
  int b   = idx / (144 * 64);
  int oh = pos / 12, ow = pos % 12;
  const float* ip = in + (size_t)b * 9000 + (oh * 2) * 30 + ow * 2;
  const float* wp = w + co * 640;
  float acc = bias[co];
  for (int ci = 0; ci < 10; ci++) {
#pragma unroll
    for (int kh = 0; kh < 8; kh++) {
      const float* r  = ip + ci * 900 + kh * 30;
      const float* wr = wp + ci * 64 + kh * 8;
#pragma unroll
      for (int kw = 0; kw < 8; kw++) acc += r[kw] * wr[kw];
    }
  }
  out[idx] = fmaxf(acc, 0.f);
}

// ---------------------------------------------------------------------------
// conv2: in (512,64,12,12), w (128,64,4,4), stride 2 -> out (512,128,5,5), relu
// ---------------------------------------------------------------------------
__global__ __launch_bounds__(256) void conv2_k(
    const float* __restrict__ in, const float* __restrict__ w,
    const float* __restrict__ bias, float* __restrict__ out) {
  int idx = blockIdx.x * 256 + threadIdx.x;     // 512*128*25 total, exact
  int pos = idx % 25;
  int co  = (idx / 25) & 127;
  int b   = idx / 3200;
  int oh = pos / 5, ow = pos % 5;
  const float* ip = in + (size_t)b * 9216 + (oh * 2) * 12 + ow * 2;
  const float* wp = w + co * 1024;
  float acc = bias[co];
  for (int ci = 0; ci < 64; ci++) {
#pragma unroll
    for (int kh = 0; kh < 4; kh++) {
      const float* r  = ip + ci * 144 + kh * 12;
      const float* wr = wp + ci * 16 + kh * 4;
#pragma unroll
      for (int kw = 0; kw < 4; kw++) acc += r[kw] * wr[kw];
    }
  }
  out[idx] = fmaxf(acc, 0.f);
}

// ---------------------------------------------------------------------------
// Generic fp32 GEMM: C[m*ldc+n] = bias[n] + sum_k X[m*K+k] * W[n*K+k]
// Requires M%64==0, N%64==0, K%16==0. 64x64 tile, 256 threads, 4x4 micro.
// ---------------------------------------------------------------------------
__global__ __launch_bounds__(256) void gemm_xwt(
    const float* __restrict__ X, const float* __restrict__ W,
    const float* __restrict__ bias, float* __restrict__ C,
    int M, int N, int K, int ldc, int relu) {
  __shared__ float Xs[16][68];
  __shared__ float Ws[16][68];
  int tid = threadIdx.x;
  int m0 = blockIdx.y * 64, n0 = blockIdx.x * 64;
  int lr = tid >> 2;            // 0..63
  int lc = (tid & 3) << 2;      // 0,4,8,12
  int tm = tid >> 4, tn = tid & 15;
  float acc[4][4] = {};
  for (int k0 = 0; k0 < K; k0 += 16) {
    const float4 xv = *(const float4*)(X + (size_t)(m0 + lr) * K + k0 + lc);
    const float4 wv = *(const float4*)(W + (size_t)(n0 + lr) * K + k0 + lc);
    Xs[lc + 0][lr] = xv.x; Xs[lc + 1][lr] = xv.y;
    Xs[lc + 2][lr] = xv.z; Xs[lc + 3][lr] = xv.w;
    Ws[lc + 0][lr] = wv.x; Ws[lc + 1][lr] = wv.y;
    Ws[lc + 2][lr] = wv.z; Ws[lc + 3][lr] = wv.w;
    __syncthreads();
#pragma unroll
    for (int kk = 0; kk < 16; kk++) {
      float a[4], bb[4];
#pragma unroll
      for (int i = 0; i < 4; i++) a[i] = Xs[kk][tm * 4 + i];
#pragma unroll
      for (int j = 0; j < 4; j++) bb[j] = Ws[kk][tn * 4 + j];
#pragma unroll
      for (int i = 0; i < 4; i++)
#pragma unroll
        for (int j = 0; j < 4; j++) acc[i][j] += a[i] * bb[j];
    }
    __syncthreads();
  }
#pragma unroll
  for (int i = 0; i < 4; i++) {
    int m = m0 + tm * 4 + i;
#pragma unroll
    for (int j = 0; j < 4; j++) {
      int n = n0 + tn * 4 + j;
      float v = acc[i][j] + bias[n];
      if (relu) v = fmaxf(v, 0.f);
      C[(size_t)m * ldc + n] = v;
    }
  }
}

// ---------------------------------------------------------------------------
// gi0 = seq @ wih0^T + bih0 where seq[s] = uf[s&511, s>>9, :]  (K=8).
// Block: 384 threads (one per output col), 32 consecutive s per block.
// ---------------------------------------------------------------------------
__global__ __launch_bounds__(384) void gi0_k(
    const float* __restrict__ uf,   // (512,64,8)
    const float* __restrict__ wih,  // (384,8)
    const float* __restrict__ bih,  // (384)
    float* __restrict__ gi) {       // (32768,384)
  int n = threadIdx.x;
  int s0 = blockIdx.x * 32;
  __shared__ float xs[32][8];
  if (n < 256) {
    int ss = s0 + (n >> 3);
    int k = n & 7;
    xs[n >> 3][k] = uf[(size_t)(ss & 511) * 512 + (ss >> 9) * 8 + k];
  }
  float w[8];
#pragma unroll
  for (int k = 0; k < 8; k++) w[k] = wih[n * 8 + k];
  float b = bih[n];
  __syncthreads();
#pragma unroll 4
  for (int i = 0; i < 32; i++) {
    float a = b;
#pragma unroll
    for (int k = 0; k < 8; k++) a += w[k] * xs[i][k];
    gi[(size_t)(s0 + i) * 384 + n] = a;
  }
}

// ---------------------------------------------------------------------------
// GRU scan, round-4 structure. 256 threads = 128 output pairs.
// Lane pair (2o, 2o+1) splits K=128; 96 v_dot2_f32_f16 per thread, combined
// with one __shfl_xor(.,1) (DPP) per gate. h ping-pongs hbuf0/hbuf1 with ONE
// barrier per step (s_waitcnt lgkmcnt(0) only -- global prefetch loads stay
// in flight across the barrier). gi rows prefetched into 4 independent
// register buffer sets (A,B,C,D): each reload is issued ~3 steps + 4 barriers
// (~1300 cyc) before its use, covering L3/HBM miss latency (~450-900 cyc).
// ---------------------------------------------------------------------------
#define GRU_STEP(HIN, HOUT, G0, G1, G2, SIDX)                                 \
  {                                                                           \
    const float4* hp4 = (const float4*)(&HIN[half * 64]);                     \
    float ar = br, az = bz, an = bn;                                          \
    _Pragma("unroll")                                                         \
    for (int q = 0; q < 8; q++) {                                             \
      float4 blk = hp4[q];                                                    \
      h2_t x0 = f2h2bits(blk.x), x1 = f2h2bits(blk.y);                        \
      h2_t x2 = f2h2bits(blk.z), x3 = f2h2bits(blk.w);                        \
      ar = fdot2(wr[4*q+0], x0, ar); az = fdot2(wz[4*q+0], x0, az);           \
      an = fdot2(wn[4*q+0], x0, an);                                          \
      ar = fdot2(wr[4*q+1], x1, ar); az = fdot2(wz[4*q+1], x1, az);           \
      an = fdot2(wn[4*q+1], x1, an);                                          \
      ar = fdot2(wr[4*q+2], x2, ar); az = fdot2(wz[4*q+2], x2, az);           \
      an = fdot2(wn[4*q+2], x2, an);                                          \
      ar = fdot2(wr[4*q+3], x3, ar); az = fdot2(wz[4*q+3], x3, az);           \
      an = fdot2(wn[4*q+3], x3, an);                                          \
    }                                                                         \
    ar += __shfl_xor(ar, 1); az += __shfl_xor(az, 1); an += __shfl_xor(an, 1);\
    float r = sigmoidf_((G0) + ar);                                           \
    float z = sigmoidf_((G1) + az);                                           \
    float n = tanhf_((G2) + r * an);                                          \
    float hn = (1.f - z) * n + z * hreg;                                      \
    hreg = hn;                                                                \
    HOUT[o] = (_Float16)hn;                                                   \
    if (LAYER == 0) {                                                         \
      if (half == 0) h_out[(size_t)(SIDX) * 128 + o] = hn;                    \
    } else if ((SIDX) >= S - 512) {                                           \
      if (half == 0) jx[(size_t)((SIDX) - (S - 512)) * 640 + 512 + o] = hn;   \
    }                                                                         \
  }

#define GRU_RELOAD(G0, G1, G2)                                                \
  { G0 = gp[0]; G1 = gp[128]; G2 = gp[256]; gp += 384; }

#define GRU_BARRIER()                                                         \
  __builtin_amdgcn_sched_barrier(0);                                          \
  asm volatile("s_waitcnt lgkmcnt(0)" ::: "memory");                          \
  __builtin_amdgcn_s_barrier();                                               \
  __builtin_amdgcn_sched_barrier(0);

template <int LAYER>
__global__ __launch_bounds__(256, 1) void gru_scan3(
    const float* __restrict__ gi,    // (S,384), includes bih
    const float* __restrict__ whh,   // (384,128)
    const float* __restrict__ bhh,   // (384)
    float* __restrict__ h_out,       // LAYER0: h1 (S,128)
    float* __restrict__ jx) {        // LAYER1: (512,640), cols 512..639
  const int S = 32768;
  const int t = threadIdx.x;
  const int o = t >> 1;      // output index 0..127
  const int half = t & 1;    // K-half 0/1

  __shared__ _Float16 hbuf0[128];
  __shared__ _Float16 hbuf1[128];

  // preload f16-packed recurrent weights: 32 h2 per gate (this thread's half)
  h2_t wr[32], wz[32], wn[32];
  {
    const float2* pr = (const float2*)(whh + (size_t)(o)       * 128 + half * 64);
    const float2* pz = (const float2*)(whh + (size_t)(128 + o) * 128 + half * 64);
    const float2* pn = (const float2*)(whh + (size_t)(256 + o) * 128 + half * 64);
#pragma unroll
    for (int k = 0; k < 32; k++) {
      float2 a = pr[k], b = pz[k], c = pn[k];
      h2_t va; va.x = (_Float16)a.x; va.y = (_Float16)a.y; wr[k] = va;
      h2_t vb; vb.x = (_Float16)b.x; vb.y = (_Float16)b.y; wz[k] = vb;
      h2_t vc; vc.x = (_Float16)c.x; vc.y = (_Float16)c.y; wn[k] = vc;
    }
  }
  // bhh folded into the matvec accumulator init (half 0 only, to count once)
  float br = half ? 0.f : bhh[o];
  float bz = half ? 0.f : bhh[128 + o];
  float bn = half ? 0.f : bhh[256 + o];

  float hreg = 0.f;
  if (t < 128) { hbuf0[t] = (_Float16)0.f; }

  // depth-4 register prefetch of gi rows (rolling pointer, +384 f per step)
  const float* gp = gi + o;
  float gA0, gA1, gA2, gB0, gB1, gB2, gC0, gC1, gC2, gD0, gD1, gD2;
  GRU_RELOAD(gA0, gA1, gA2);
  GRU_RELOAD(gB0, gB1, gB2);
  GRU_RELOAD(gC0, gC1, gC2);
  GRU_RELOAD(gD0, gD1, gD2);
  __syncthreads();

  // NOTE: in the last iteration the reloads read rows S..S+3, which land in
  // the h1 region of d_ws -- in-bounds, values never consumed.
  for (int s = 0; s < S; s += 4) {
    GRU_STEP(hbuf0, hbuf1, gA0, gA1, gA2, s);
    GRU_RELOAD(gA0, gA1, gA2);
    GRU_BARRIER();
    GRU_STEP(hbuf1, hbuf0, gB0, gB1, gB2, s + 1);
    GRU_RELOAD(gB0, gB1, gB2);
    GRU_BARRIER();
    GRU_STEP(hbuf0, hbuf1, gC0, gC1, gC2, s + 2);
    GRU_RELOAD(gC0, gC1, gC2);
    GRU_BARRIER();
    GRU_STEP(hbuf1, hbuf0, gD0, gD1, gD2, s + 3);
    GRU_RELOAD(gD0, gD1, gD2);
    GRU_BARRIER();
  }
}

// ---------------------------------------------------------------------------
// out head: out[b,:] = hidden[b,:] @ out_w.T + out_b (relu pre-applied)
// ---------------------------------------------------------------------------
__global__ __launch_bounds__(64) void out_k(
    const float* __restrict__ hidden, const float* __restrict__ ow,
    const float* __restrict__ ob, float* __restrict__ out) {
  __shared__ float hrow[512];
  int b = blockIdx.x, t = threadIdx.x;
  float4* h4 = (float4*)hrow;
  const float4* src = (const float4*)(hidden + (size_t)b * 512);
  h4[t] = src[t];
  h4[t + 64] = src[t + 64];
  __syncthreads();
  if (t < 12) {
    float acc = ob[t];
    const float* wr = ow + t * 512;
    for (int k = 0; k < 512; k++) acc += hrow[k] * wr[k];
    out[(size_t)b * 12 + t] = acc;
  }
}

// ---------------------------------------------------------------------------
extern "C" void kernel_launch(void* const* d_in, const int* in_sizes, int n_in,
                              void* d_out, int out_size, void* d_ws,
                              size_t ws_size, hipStream_t stream) {
  const float* gf    = (const float*)d_in[0];   // (512,10,30,30)
  const float* uf    = (const float*)d_in[1];   // (512,64,8)
  const float* c1w   = (const float*)d_in[2];
  const float* c1b   = (const float*)d_in[3];
  const float* c2w   = (const float*)d_in[4];
  const float* c2b   = (const float*)d_in[5];
  const float* ffw   = (const float*)d_in[6];
  const float* ffb   = (const float*)d_in[7];
  const float* wih0  = (const float*)d_in[8];
  const float* whh0  = (const float*)d_in[9];
  const float* bih0  = (const float*)d_in[10];
  const float* bhh0  = (const float*)d_in[11];
  const float* wih1  = (const float*)d_in[12];
  const float* whh1  = (const float*)d_in[13];
  const float* bih1  = (const float*)d_in[14];
  const float* bhh1  = (const float*)d_in[15];
  const float* jw    = (const float*)d_in[16];
  const float* jb    = (const float*)d_in[17];
  const float* ow    = (const float*)d_in[18];
  const float* ob    = (const float*)d_in[19];
  float* outp = (float*)d_out;                  // (512,12)

  // workspace layout (floats). gi buffer time-shares with conv scratch
  // (conv1o/conv2o dead before gi0 is written) and is reused for gi1.
  float* ws     = (float*)d_ws;
  float* gi     = ws;                 // 32768*384 = 12,582,912 f
  float* conv1o = ws;                 //  4,718,592 f (aliases gi, earlier)
  float* conv2o = ws + 4718592;       //  1,638,400 f (aliases gi, earlier)
  float* h1     = ws + 12582912;      //  4,194,304 f
  float* jx     = h1 + 4194304;       //  512*640 = 327,680 f
  float* hidden = jx + 327680;        //  512*512 = 262,144 f
  // total: 17,367,040 floats = ~66.3 MB

  conv1_k<<<18432, 256, 0, stream>>>(gf, c1w, c1b, conv1o);
  conv2_k<<<6400, 256, 0, stream>>>(conv1o, c2w, c2b, conv2o);
  // glob = conv2o(512,3200) @ ffw.T + ffb -> jx cols [0,512)
  gemm_xwt<<<dim3(8, 8), 256, 0, stream>>>(conv2o, ffw, ffb, jx,
                                           512, 512, 3200, 640, 0);
  // gi0 = seq @ wih0^T + bih0  (overwrites conv scratch, now dead)
  gi0_k<<<1024, 384, 0, stream>>>(uf, wih0, bih0, gi);
  // GRU layer 0
  gru_scan3<0><<<1, 256, 0, stream>>>(gi, whh0, bhh0, h1, nullptr);
  // gi1 = h1(32768,128) @ wih1.T + bih1  (overwrites gi0, now dead)
  gemm_xwt<<<dim3(6, 512), 256, 0, stream>>>(h1, wih1, bih1, gi,
                                             32768, 384, 128, 384, 0);
  // GRU layer 1, writes last 512 h's into jx cols [512,640)
  gru_scan3<1><<<1, 256, 0, stream>>>(gi, whh1, bhh1, nullptr, jx);
  // hidden = relu(jx(512,640) @ jw.T + jb)
  gemm_xwt<<<dim3(8, 8), 256, 0, stream>>>(jx, jw, jb, hidden,
                                           512, 512, 640, 512, 1);
  out_k<<<512, 64, 0, stream>>>(hidden, ow, ob, outp);
}